// Round 1
// baseline (401.788 us; speedup 1.0000x reference)
//
#include <hip/hip_runtime.h>
#include <hip/hip_bf16.h>

#define K1 784
#define N1 100
#define BM 64
#define BK 56
#define NT 320
#define XS_STRIDE 68   // 68*4=272B: 16B-aligned rows, bank-spread transpose writes

// ---------------------------------------------------------------------------
// Kernel 1: fold conv (linear, VALID, 3x3) into w1 -> W_eff[784][100]
// W_eff[p][j] = sum_{dy,dx valid} conv_w[dy][dx] * w1[(py-dy)*26+(px-dx)][j]
// ---------------------------------------------------------------------------
__global__ void build_weff(const float* __restrict__ w1,
                           const float* __restrict__ conv_w,
                           float* __restrict__ weff) {
    int idx = blockIdx.x * blockDim.x + threadIdx.x;
    if (idx >= K1 * N1) return;
    int p = idx / N1, j = idx % N1;
    int py = p / 28, px = p % 28;
    float acc = 0.f;
    #pragma unroll
    for (int dy = 0; dy < 3; ++dy) {
        int oy = py - dy;
        if (oy < 0 || oy > 25) continue;
        #pragma unroll
        for (int dx = 0; dx < 3; ++dx) {
            int ox = px - dx;
            if (ox < 0 || ox > 25) continue;
            acc += conv_w[dy * 3 + dx] * w1[(oy * 26 + ox) * N1 + j];
        }
    }
    weff[idx] = acc;
}

// ---------------------------------------------------------------------------
// Kernel 2: fused  relu(x@Weff+b1) @ w2 ... fully in one block per 64 rows.
// 320 threads = 16 row-threads (4 rows each, float4 LDS read)
//             x 20 col-threads (5 cols each, exactly 100 cols)
// ---------------------------------------------------------------------------
__global__ __launch_bounds__(NT) void fused_mlp(
    const float* __restrict__ x,
    const float* __restrict__ weff,
    const float* __restrict__ b1,
    const float* __restrict__ w2,
    const float* __restrict__ b2,
    const float* __restrict__ w3,
    const float* __restrict__ b3,
    float* __restrict__ out)
{
    // big region: x-tile [BK][XS_STRIDE] | w-tile [BK][N1]; reused as h1[64][100]
    __shared__ float smem[BK * XS_STRIDE + BK * N1];
    __shared__ float w2s[N1 * 10];
    __shared__ float b1s[N1];
    __shared__ float w3s[10 * 10];
    __shared__ float b2s[16];
    __shared__ float b3s[16];
    __shared__ float h2s[BM * 10];

    float* xs  = smem;                  // [BK][XS_STRIDE], k-major (transposed)
    float* wsh = smem + BK * XS_STRIDE; // [BK][N1]
    float* h1s = smem;                  // reuse after main loop

    const int tid  = threadIdx.x;
    const int row0 = blockIdx.x * BM;

    // stage small params (used only after many barriers)
    for (int e = tid; e < N1 * 10; e += NT) w2s[e] = w2[e];
    for (int e = tid; e < N1; e += NT)      b1s[e] = b1[e];
    for (int e = tid; e < 100; e += NT)     w3s[e] = w3[e];
    if (tid < 10) { b2s[tid] = b2[tid]; b3s[tid] = b3[tid]; }

    const int c_t = tid % 20;  // col-thread: cols c_t*5 .. c_t*5+4
    const int r_t = tid / 20;  // row-thread: rows r_t*4 .. r_t*4+3

    float acc[4][5];
    #pragma unroll
    for (int i = 0; i < 4; ++i)
        #pragma unroll
        for (int m = 0; m < 5; ++m) acc[i][m] = 0.f;

    for (int t = 0; t < K1 / BK; ++t) {
        __syncthreads();
        // stage x tile, transposed to k-major: xs[kk][row]
        for (int e = tid; e < BM * (BK / 4); e += NT) {   // 64*14 = 896 float4
            int r = e / (BK / 4), kq = e % (BK / 4);
            const float4 v = *reinterpret_cast<const float4*>(
                &x[(size_t)(row0 + r) * K1 + t * BK + kq * 4]);
            int kk = kq * 4;
            xs[(kk + 0) * XS_STRIDE + r] = v.x;
            xs[(kk + 1) * XS_STRIDE + r] = v.y;
            xs[(kk + 2) * XS_STRIDE + r] = v.z;
            xs[(kk + 3) * XS_STRIDE + r] = v.w;
        }
        // stage w tile: wsh[kk][col], same layout as global -> float4 copy
        for (int e = tid; e < BK * (N1 / 4); e += NT) {   // 56*25 = 1400 float4
            int kk = e / (N1 / 4), cq = e % (N1 / 4);
            const float4 v = *reinterpret_cast<const float4*>(
                &weff[(size_t)(t * BK + kk) * N1 + cq * 4]);
            *reinterpret_cast<float4*>(&wsh[kk * N1 + cq * 4]) = v;
        }
        __syncthreads();

        #pragma unroll 8
        for (int kk = 0; kk < BK; ++kk) {
            const float4 xf = *reinterpret_cast<const float4*>(
                &xs[kk * XS_STRIDE + r_t * 4]);
            const float xr[4] = {xf.x, xf.y, xf.z, xf.w};
            const float* wr = &wsh[kk * N1 + c_t * 5];
            float wv[5];
            #pragma unroll
            for (int m = 0; m < 5; ++m) wv[m] = wr[m];
            #pragma unroll
            for (int i = 0; i < 4; ++i)
                #pragma unroll
                for (int m = 0; m < 5; ++m)
                    acc[i][m] += xr[i] * wv[m];
        }
    }

    __syncthreads();   // all tile reads done; smem region now reusable
    // h1 = relu(acc + b1)
    #pragma unroll
    for (int i = 0; i < 4; ++i) {
        int row = r_t * 4 + i;
        #pragma unroll
        for (int m = 0; m < 5; ++m) {
            int col = c_t * 5 + m;
            h1s[row * N1 + col] = fmaxf(acc[i][m] + b1s[col], 0.f);
        }
    }
    __syncthreads();

    // layer 2: h2 = relu(h1 @ w2 + b2)   (64 rows x 10 cols = 640 outputs)
    for (int p = tid; p < BM * 10; p += NT) {
        int row = p / 10, j = p % 10;
        float s = b2s[j];
        const float* hr = &h1s[row * N1];
        #pragma unroll 10
        for (int k = 0; k < N1; ++k) s += hr[k] * w2s[k * 10 + j];
        h2s[p] = fmaxf(s, 0.f);
    }
    __syncthreads();

    // layer 3: out = h2 @ w3 + b3
    for (int p = tid; p < BM * 10; p += NT) {
        int row = p / 10, j = p % 10;
        float s = b3s[j];
        const float* hr = &h2s[row * 10];
        #pragma unroll
        for (int k = 0; k < 10; ++k) s += hr[k] * w3s[k * 10 + j];
        out[(size_t)row0 * 10 + p] = s;
    }
}

extern "C" void kernel_launch(void* const* d_in, const int* in_sizes, int n_in,
                              void* d_out, int out_size, void* d_ws, size_t ws_size,
                              hipStream_t stream) {
    const float* x     = (const float*)d_in[0];
    const float* convw = (const float*)d_in[1];
    const float* w1    = (const float*)d_in[2];
    const float* b1    = (const float*)d_in[3];
    const float* w2    = (const float*)d_in[4];
    const float* b2    = (const float*)d_in[5];
    const float* w3    = (const float*)d_in[6];
    const float* b3    = (const float*)d_in[7];
    float* out  = (float*)d_out;
    float* weff = (float*)d_ws;   // 784*100*4 = 313,600 B scratch

    build_weff<<<(K1 * N1 + 255) / 256, 256, 0, stream>>>(w1, convw, weff);
    fused_mlp<<<65536 / BM, NT, 0, stream>>>(x, weff, b1, w2, b2, w3, b3, out);
}

// Round 2
// 79.054 us; speedup vs baseline: 5.0824x; 5.0824x over previous
//
#include <hip/hip_runtime.h>
#include <hip/hip_bf16.h>

#define K1 784
#define N1 100
#define KT 25    // k-tiles of 32 (K padded to 800; pad rows are zero in packed W)
#define NTT 7    // n-tiles of 16 (N padded to 112; pad cols zero)

typedef __attribute__((ext_vector_type(8))) short bf16x8;
typedef __attribute__((ext_vector_type(4))) float f32x4;

__device__ __forceinline__ ushort f2bf(float f) {
    union { float f; unsigned u; } v; v.f = f;
    unsigned u = v.u;
    return (ushort)((u + 0x7FFFu + ((u >> 16) & 1u)) >> 16);   // RNE
}
__device__ __forceinline__ float bf2f(ushort h) {
    union { unsigned u; float f; } v; v.u = ((unsigned)h) << 16;
    return v.f;
}

// ---------------------------------------------------------------------------
// Kernel 1: fold conv into w1 -> W_eff[k][n], split hi/lo bf16, and store in
// MFMA B-fragment order: wp[(kt*7+nt)*2 + hl][lane][j] with
//   k = kt*32 + (lane>>4)*8 + j   (same k-map the main kernel uses for A)
//   n = nt*16 + (lane&15)
// Total: 25*7*2*512 ushorts = 358,400 B in d_ws.
// ---------------------------------------------------------------------------
__global__ void build_wp(const float* __restrict__ w1,
                         const float* __restrict__ conv_w,
                         ushort* __restrict__ wp) {
    int idx = blockIdx.x * blockDim.x + threadIdx.x;
    if (idx >= KT * NTT * 512) return;          // 89,600 threads
    int j = idx & 7, lane = (idx >> 3) & 63, rest = idx >> 9;
    int nt = rest % NTT, kt = rest / NTT;
    int k = kt * 32 + (lane >> 4) * 8 + j;
    int n = nt * 16 + (lane & 15);
    float w = 0.f;
    if (k < K1 && n < N1) {
        int py = k / 28, px = k % 28;
        #pragma unroll
        for (int dy = 0; dy < 3; ++dy) {
            int oy = py - dy; if (oy < 0 || oy > 25) continue;
            #pragma unroll
            for (int dx = 0; dx < 3; ++dx) {
                int ox = px - dx; if (ox < 0 || ox > 25) continue;
                w += conv_w[dy * 3 + dx] * w1[(oy * 26 + ox) * N1 + n];
            }
        }
    }
    ushort hi = f2bf(w);
    ushort lo = f2bf(w - bf2f(hi));
    int base = (kt * NTT + nt) * 2;
    wp[(size_t)(base + 0) * 512 + lane * 8 + j] = hi;
    wp[(size_t)(base + 1) * 512 + lane * 8 + j] = lo;
}

// ---------------------------------------------------------------------------
// Kernel 2: one wave per 32 rows. K-loop is LDS-free: A from global fp32
// (converted to bf16 hi/lo in-register), B-frags from L2-resident packed W.
// 3-product split: Ahi*Bhi + Alo*Bhi + Ahi*Blo  (fp32-level accuracy).
// Epilogue: h1->LDS, layers 2/3 per-wave.
// ---------------------------------------------------------------------------
__global__ __launch_bounds__(64) void fused_mfma(
    const float* __restrict__ x, const ushort* __restrict__ wp,
    const float* __restrict__ b1, const float* __restrict__ w2,
    const float* __restrict__ b2, const float* __restrict__ w3,
    const float* __restrict__ b3, float* __restrict__ out)
{
    __shared__ __attribute__((aligned(16))) float h1s[32][100];
    __shared__ __attribute__((aligned(16))) float w2t[10][100];  // transposed w2
    __shared__ float w3s[100];
    __shared__ float b1s[100];
    __shared__ float b2s[10], b3s[10];
    __shared__ float h2s[320];

    const int lane = threadIdx.x;
    const int lo16 = lane & 15, hi4 = lane >> 4;
    const size_t row0 = (size_t)blockIdx.x * 32;

    // stage epilogue params (consumed only after the post-K-loop barrier)
    for (int e = lane; e < 1000; e += 64) w2t[e % 10][e / 10] = w2[e];
    for (int e = lane; e < 100; e += 64) { w3s[e] = w3[e]; b1s[e] = b1[e]; }
    if (lane < 10) { b2s[lane] = b2[lane]; b3s[lane] = b3[lane]; }

    const float* xr0 = x + (row0 + lo16) * K1;        // m-tile 0: rows row0..+15
    const float* xr1 = x + (row0 + 16 + lo16) * K1;   // m-tile 1

    f32x4 acc[2][NTT];
    #pragma unroll
    for (int m = 0; m < 2; ++m)
        #pragma unroll
        for (int n = 0; n < NTT; ++n) {
            f32x4 z = {0.f, 0.f, 0.f, 0.f};
            acc[m][n] = z;
        }

    for (int kt = 0; kt < KT; ++kt) {
        int kb = kt * 32 + hi4 * 8;
        if (kb > K1 - 8) kb = K1 - 8;   // kt=24, hi4>=2: clamp (B is zero there)
        float4 p0 = *reinterpret_cast<const float4*>(xr0 + kb);
        float4 p1 = *reinterpret_cast<const float4*>(xr0 + kb + 4);
        float4 q0 = *reinterpret_cast<const float4*>(xr1 + kb);
        float4 q1 = *reinterpret_cast<const float4*>(xr1 + kb + 4);

        float f0[8] = {p0.x,p0.y,p0.z,p0.w,p1.x,p1.y,p1.z,p1.w};
        float f1[8] = {q0.x,q0.y,q0.z,q0.w,q1.x,q1.y,q1.z,q1.w};
        bf16x8 ah0, al0, ah1, al1;
        #pragma unroll
        for (int j = 0; j < 8; ++j) {
            ushort h = f2bf(f0[j]);
            ah0[j] = (short)h; al0[j] = (short)f2bf(f0[j] - bf2f(h));
            ushort g = f2bf(f1[j]);
            ah1[j] = (short)g; al1[j] = (short)f2bf(f1[j] - bf2f(g));
        }

        const ushort* wpt = wp + (size_t)kt * NTT * 1024;
        #pragma unroll
        for (int nt = 0; nt < NTT; ++nt) {
            bf16x8 bh = *reinterpret_cast<const bf16x8*>(wpt + (nt*2+0)*512 + lane*8);
            bf16x8 bl = *reinterpret_cast<const bf16x8*>(wpt + (nt*2+1)*512 + lane*8);
            acc[0][nt] = __builtin_amdgcn_mfma_f32_16x16x32_bf16(ah0, bh, acc[0][nt], 0,0,0);
            acc[1][nt] = __builtin_amdgcn_mfma_f32_16x16x32_bf16(ah1, bh, acc[1][nt], 0,0,0);
            acc[0][nt] = __builtin_amdgcn_mfma_f32_16x16x32_bf16(al0, bh, acc[0][nt], 0,0,0);
            acc[1][nt] = __builtin_amdgcn_mfma_f32_16x16x32_bf16(al1, bh, acc[1][nt], 0,0,0);
            acc[0][nt] = __builtin_amdgcn_mfma_f32_16x16x32_bf16(ah0, bl, acc[0][nt], 0,0,0);
            acc[1][nt] = __builtin_amdgcn_mfma_f32_16x16x32_bf16(ah1, bl, acc[1][nt], 0,0,0);
        }
    }

    // ---- epilogue: h1 = relu(acc + b1) -> LDS  (C layout: col=lane&15,
    // row=(lane>>4)*4+reg — HW-verified mapping)
    #pragma unroll
    for (int m = 0; m < 2; ++m)
        #pragma unroll
        for (int nt = 0; nt < NTT; ++nt) {
            int col = nt * 16 + lo16;
            if (col < N1) {
                #pragma unroll
                for (int r = 0; r < 4; ++r)
                    h1s[m*16 + hi4*4 + r][col] = fmaxf(acc[m][nt][r] + b1s[col], 0.f);
            }
        }
    __syncthreads();

    // ---- layer 2: h2 = relu(h1 @ w2 + b2), 320 outputs over 64 lanes
    #pragma unroll
    for (int q = 0; q < 5; ++q) {
        int p = lane + q * 64;
        int row = p / 10, jj = p % 10;
        const float* hr = &h1s[row][0];
        const float* wr = &w2t[jj][0];
        float4 a4 = {0.f, 0.f, 0.f, 0.f};
        #pragma unroll 5
        for (int k4 = 0; k4 < N1; k4 += 4) {
            float4 hv = *reinterpret_cast<const float4*>(hr + k4);
            float4 wv = *reinterpret_cast<const float4*>(wr + k4);
            a4.x += hv.x * wv.x; a4.y += hv.y * wv.y;
            a4.z += hv.z * wv.z; a4.w += hv.w * wv.w;
        }
        h2s[p] = fmaxf(b2s[jj] + a4.x + a4.y + a4.z + a4.w, 0.f);
    }
    __syncthreads();

    // ---- layer 3: out = h2 @ w3 + b3
    #pragma unroll
    for (int q = 0; q < 5; ++q) {
        int p = lane + q * 64;
        int row = p / 10, jj = p % 10;
        float s = b3s[jj];
        #pragma unroll
        for (int k = 0; k < 10; ++k) s += h2s[row*10 + k] * w3s[k*10 + jj];
        out[row0 * 10 + p] = s;   // = (row0+row)*10 + jj, coalesced
    }
}

extern "C" void kernel_launch(void* const* d_in, const int* in_sizes, int n_in,
                              void* d_out, int out_size, void* d_ws, size_t ws_size,
                              hipStream_t stream) {
    const float* x     = (const float*)d_in[0];
    const float* convw = (const float*)d_in[1];
    const float* w1    = (const float*)d_in[2];
    const float* b1    = (const float*)d_in[3];
    const float* w2    = (const float*)d_in[4];
    const float* b2    = (const float*)d_in[5];
    const float* w3    = (const float*)d_in[6];
    const float* b3    = (const float*)d_in[7];
    float* out  = (float*)d_out;
    ushort* wp  = (ushort*)d_ws;   // 358,400 B packed W_eff frags

    build_wp<<<(KT * NTT * 512 + 255) / 256, 256, 0, stream>>>(w1, convw, wp);
    fused_mfma<<<65536 / 32, 64, 0, stream>>>(x, wp, b1, w2, b2, w3, b3, out);
}

// Round 3
// 71.207 us; speedup vs baseline: 5.6425x; 1.1102x over previous
//
#include <hip/hip_runtime.h>
#include <hip/hip_bf16.h>

#define K1 784
#define N1 100
#define KT 25    // k-tiles of 32 (K padded to 800; pad rows zero in packed W)
#define NTT 7    // n-tiles of 16 (N padded to 112; pad cols zero)

typedef __attribute__((ext_vector_type(8))) short bf16x8;
typedef __attribute__((ext_vector_type(4))) float f32x4;

__device__ __forceinline__ ushort f2bf(float f) {
    union { float f; unsigned u; } v; v.f = f;
    unsigned u = v.u;
    return (ushort)((u + 0x7FFFu + ((u >> 16) & 1u)) >> 16);   // RNE
}
__device__ __forceinline__ float bf2f(ushort h) {
    union { unsigned u; float f; } v; v.u = ((unsigned)h) << 16;
    return v.f;
}

// ---------------------------------------------------------------------------
// Kernel 1: fold conv into w1 -> W_eff[k][n] (bf16 hi only), stored in MFMA
// B-fragment order: wp[(kt*7+nt)*512 + lane*8 + j] with
//   k = kt*32 + (lane>>4)*8 + j, n = nt*16 + (lane&15).  179,200 B total.
// ---------------------------------------------------------------------------
__global__ void build_wp(const float* __restrict__ w1,
                         const float* __restrict__ conv_w,
                         ushort* __restrict__ wp) {
    int idx = blockIdx.x * blockDim.x + threadIdx.x;
    if (idx >= KT * NTT * 512) return;
    int j = idx & 7, lane = (idx >> 3) & 63, rest = idx >> 9;
    int nt = rest % NTT, kt = rest / NTT;
    int k = kt * 32 + (lane >> 4) * 8 + j;
    int n = nt * 16 + (lane & 15);
    float w = 0.f;
    if (k < K1 && n < N1) {
        int py = k / 28, px = k % 28;
        #pragma unroll
        for (int dy = 0; dy < 3; ++dy) {
            int oy = py - dy; if (oy < 0 || oy > 25) continue;
            #pragma unroll
            for (int dx = 0; dx < 3; ++dx) {
                int ox = px - dx; if (ox < 0 || ox > 25) continue;
                w += conv_w[dy * 3 + dx] * w1[(oy * 26 + ox) * N1 + n];
            }
        }
    }
    wp[(size_t)(kt * NTT + nt) * 512 + lane * 8 + j] = f2bf(w);
}

// ---------------------------------------------------------------------------
// Kernel 2: one 64-thread wave per 16 rows, 4096 blocks (16 waves/CU).
// K-loop: x from global (prefetched one kt ahead, hi/lo bf16 split in-reg),
// B (hi-only) from L2-resident packed W. 2 MFMA per nt. No LDS in hot loop.
// Epilogue: shuffle-reduce layers 2/3, tiny LDS for w2t/w3/b*.
// ---------------------------------------------------------------------------
__global__ __launch_bounds__(64) void fused_mfma(
    const float* __restrict__ x, const ushort* __restrict__ wp,
    const float* __restrict__ b1, const float* __restrict__ w2,
    const float* __restrict__ b2, const float* __restrict__ w3,
    const float* __restrict__ b3, float* __restrict__ out)
{
    __shared__ float w2t[10][112];   // transposed w2, padded cols 100..111 = 0
    __shared__ float w3s[100];
    __shared__ float b1s[100];
    __shared__ float b2s[10], b3s[10];

    const int lane = threadIdx.x;
    const int lo16 = lane & 15, hi4 = lane >> 4;
    const size_t row0 = (size_t)blockIdx.x * 16;

    // stage epilogue params (single wave: consumed after one barrier at end)
    for (int e = lane; e < 10 * 112; e += 64) w2t[e / 112][e % 112] = 0.f;
    __syncthreads();   // single-wave barrier: effectively free
    for (int e = lane; e < 1000; e += 64) w2t[e % 10][e / 10] = w2[e];
    for (int e = lane; e < 100; e += 64) { w3s[e] = w3[e]; b1s[e] = b1[e]; }
    if (lane < 10) { b2s[lane] = b2[lane]; b3s[lane] = b3[lane]; }

    const float* xr = x + (row0 + lo16) * K1;

    f32x4 acc[NTT];
    #pragma unroll
    for (int n = 0; n < NTT; ++n) { f32x4 z = {0.f,0.f,0.f,0.f}; acc[n] = z; }

    // prefetch kt=0 (always in-range)
    float4 c0 = *reinterpret_cast<const float4*>(xr + hi4 * 8);
    float4 c1 = *reinterpret_cast<const float4*>(xr + hi4 * 8 + 4);

    for (int kt = 0; kt < KT; ++kt) {
        float4 n0 = c0, n1 = c1;
        if (kt < KT - 1) {
            int nb = (kt + 1) * 32 + hi4 * 8;
            if (nb > K1 - 8) nb = K1 - 8;   // pad region: B rows are zero there
            n0 = *reinterpret_cast<const float4*>(xr + nb);
            n1 = *reinterpret_cast<const float4*>(xr + nb + 4);
        }

        float f[8] = {c0.x,c0.y,c0.z,c0.w,c1.x,c1.y,c1.z,c1.w};
        bf16x8 ah, al;
        #pragma unroll
        for (int j = 0; j < 8; ++j) {
            ushort h = f2bf(f[j]);
            ah[j] = (short)h;
            al[j] = (short)f2bf(f[j] - bf2f(h));
        }

        const ushort* wpt = wp + (size_t)kt * NTT * 512 + lane * 8;
        #pragma unroll
        for (int nt = 0; nt < NTT; ++nt) {
            bf16x8 bh = *reinterpret_cast<const bf16x8*>(wpt + nt * 512);
            acc[nt] = __builtin_amdgcn_mfma_f32_16x16x32_bf16(ah, bh, acc[nt], 0,0,0);
            acc[nt] = __builtin_amdgcn_mfma_f32_16x16x32_bf16(al, bh, acc[nt], 0,0,0);
        }
        c0 = n0; c1 = n1;
    }

    __syncthreads();   // order staging writes vs epilogue reads (1 wave: free)

    // ---- h1 = relu(acc + b1) in registers.
    // C layout (HW-verified): col = nt*16+lo16, row = hi4*4 + r
    float h1v[NTT][4];
    #pragma unroll
    for (int nt = 0; nt < NTT; ++nt) {
        int col = nt * 16 + lo16;
        bool valid = col < N1;
        float bb = valid ? b1s[valid ? col : 0] : 0.f;
        #pragma unroll
        for (int r = 0; r < 4; ++r)
            h1v[nt][r] = valid ? fmaxf(acc[nt][r] + bb, 0.f) : 0.f;
    }

    // ---- layers 2+3 fused: per j, partial over this lane's 7 cols,
    // xor-reduce across the 16-lane group, accumulate out on the fly.
    const int jj = lo16;                 // this lane's output column (if <10)
    float o[4] = {0.f, 0.f, 0.f, 0.f};
    #pragma unroll
    for (int j = 0; j < 10; ++j) {
        float pj[4] = {0.f, 0.f, 0.f, 0.f};
        #pragma unroll
        for (int nt = 0; nt < NTT; ++nt) {
            float wv = w2t[j][nt * 16 + lo16];   // padded: 0 beyond col 99
            #pragma unroll
            for (int r = 0; r < 4; ++r) pj[r] += h1v[nt][r] * wv;
        }
        #pragma unroll
        for (int mask = 8; mask >= 1; mask >>= 1)
            #pragma unroll
            for (int r = 0; r < 4; ++r)
                pj[r] += __shfl_xor(pj[r], mask, 16);
        float w3v = (jj < 10) ? w3s[j * 10 + jj] : 0.f;
        #pragma unroll
        for (int r = 0; r < 4; ++r) {
            float h2 = fmaxf(pj[r] + b2s[j], 0.f);
            o[r] += h2 * w3v;
        }
    }

    if (jj < 10) {
        #pragma unroll
        for (int r = 0; r < 4; ++r)
            out[(row0 + hi4 * 4 + r) * 10 + jj] = o[r] + b3s[jj];
    }
}

extern "C" void kernel_launch(void* const* d_in, const int* in_sizes, int n_in,
                              void* d_out, int out_size, void* d_ws, size_t ws_size,
                              hipStream_t stream) {
    const float* x     = (const float*)d_in[0];
    const float* convw = (const float*)d_in[1];
    const float* w1    = (const float*)d_in[2];
    const float* b1    = (const float*)d_in[3];
    const float* w2    = (const float*)d_in[4];
    const float* b2    = (const float*)d_in[5];
    const float* w3    = (const float*)d_in[6];
    const float* b3    = (const float*)d_in[7];
    float* out  = (float*)d_out;
    ushort* wp  = (ushort*)d_ws;   // 179,200 B packed W_eff (bf16 hi)

    build_wp<<<(KT * NTT * 512 + 255) / 256, 256, 0, stream>>>(w1, convw, wp);
    fused_mfma<<<65536 / 16, 64, 0, stream>>>(x, wp, b1, w2, b2, w3, b3, out);
}

// Round 4
// 63.904 us; speedup vs baseline: 6.2874x; 1.1143x over previous
//
#include <hip/hip_runtime.h>
#include <hip/hip_bf16.h>

#define K1 784
#define N1 100
#define KT 25    // k-tiles of 32 (K padded to 800; pad rows zero in packed W)
#define NTT 7    // n-tiles of 16 (N padded to 112; pad cols zero)

typedef __attribute__((ext_vector_type(8))) short bf16x8;
typedef __attribute__((ext_vector_type(4))) float f32x4;

__device__ __forceinline__ ushort f2bf(float f) {
    union { float f; unsigned u; } v; v.f = f;
    unsigned u = v.u;
    return (ushort)((u + 0x7FFFu + ((u >> 16) & 1u)) >> 16);   // RNE
}

// 8x f32 -> 8x bf16 (RNE) via 4 packed converts
__device__ __forceinline__ bf16x8 pack_bf16x8(float4 a, float4 b) {
    union { unsigned u[4]; bf16x8 v; } r;
    asm("v_cvt_pk_bf16_f32 %0, %1, %2" : "=v"(r.u[0]) : "v"(a.x), "v"(a.y));
    asm("v_cvt_pk_bf16_f32 %0, %1, %2" : "=v"(r.u[1]) : "v"(a.z), "v"(a.w));
    asm("v_cvt_pk_bf16_f32 %0, %1, %2" : "=v"(r.u[2]) : "v"(b.x), "v"(b.y));
    asm("v_cvt_pk_bf16_f32 %0, %1, %2" : "=v"(r.u[3]) : "v"(b.z), "v"(b.w));
    return r.v;
}

// ---------------------------------------------------------------------------
// Kernel 1: fold conv into w1 -> W_eff[k][n] (bf16 RNE), stored in MFMA
// B-fragment order: wp[(kt*7+nt)*512 + lane*8 + j] with
//   k = kt*32 + (lane>>4)*8 + j, n = nt*16 + (lane&15).  179,200 B total.
// ---------------------------------------------------------------------------
__global__ void build_wp(const float* __restrict__ w1,
                         const float* __restrict__ conv_w,
                         ushort* __restrict__ wp) {
    int idx = blockIdx.x * blockDim.x + threadIdx.x;
    if (idx >= KT * NTT * 512) return;
    int j = idx & 7, lane = (idx >> 3) & 63, rest = idx >> 9;
    int nt = rest % NTT, kt = rest / NTT;
    int k = kt * 32 + (lane >> 4) * 8 + j;
    int n = nt * 16 + (lane & 15);
    float w = 0.f;
    if (k < K1 && n < N1) {
        int py = k / 28, px = k % 28;
        #pragma unroll
        for (int dy = 0; dy < 3; ++dy) {
            int oy = py - dy; if (oy < 0 || oy > 25) continue;
            #pragma unroll
            for (int dx = 0; dx < 3; ++dx) {
                int ox = px - dx; if (ox < 0 || ox > 25) continue;
                w += conv_w[dy * 3 + dx] * w1[(oy * 26 + ox) * N1 + n];
            }
        }
    }
    wp[(size_t)(kt * NTT + nt) * 512 + lane * 8 + j] = f2bf(w);
}

// ---------------------------------------------------------------------------
// Kernel 2: one 64-thread wave per 16 rows, 4096 blocks.
// K-loop fully register double-buffered: even/odd named B-fragment sets and
// x-vectors, prefetched one kt ahead -> MFMAs never wait on same-kt loads.
// 1 MFMA product (A-hi RNE via v_cvt_pk, B-hi from packed W).
// Epilogue: shuffle-reduce layers 2/3, tiny LDS for w2t/w3/b*.
// ---------------------------------------------------------------------------
__global__ __launch_bounds__(64, 4) void fused_mfma(
    const float* __restrict__ x, const ushort* __restrict__ wp,
    const float* __restrict__ b1, const float* __restrict__ w2,
    const float* __restrict__ b2, const float* __restrict__ w3,
    const float* __restrict__ b3, float* __restrict__ out)
{
    __shared__ float w2t[10][112];   // transposed w2, padded cols 100..111 = 0
    __shared__ float w3s[100];
    __shared__ float b1s[100];
    __shared__ float b2s[10], b3s[10];

    const int lane = threadIdx.x;
    const int lo16 = lane & 15, hi4 = lane >> 4;
    const size_t row0 = (size_t)blockIdx.x * 16;

    // stage epilogue params (single wave: consumed after one barrier at end)
    for (int e = lane; e < 10 * 112; e += 64) w2t[e / 112][e % 112] = 0.f;
    __syncthreads();   // single-wave barrier: effectively free
    for (int e = lane; e < 1000; e += 64) w2t[e % 10][e / 10] = w2[e];
    for (int e = lane; e < 100; e += 64) { w3s[e] = w3[e]; b1s[e] = b1[e]; }
    if (lane < 10) { b2s[lane] = b2[lane]; b3s[lane] = b3[lane]; }

    const float* xr = x + (row0 + lo16) * K1;
    const ushort* wl = wp + lane * 8;          // lane-fixed B base

    f32x4 acc[NTT];
    #pragma unroll
    for (int n = 0; n < NTT; ++n) { f32x4 z = {0.f,0.f,0.f,0.f}; acc[n] = z; }

    bf16x8 b_e[NTT], b_o[NTT];
    float4 ce0, ce1, co0, co1;

    // prologue: kt=0 into even set
    ce0 = *reinterpret_cast<const float4*>(xr + hi4 * 8);
    ce1 = *reinterpret_cast<const float4*>(xr + hi4 * 8 + 4);
    #pragma unroll
    for (int nt = 0; nt < NTT; ++nt)
        b_e[nt] = *reinterpret_cast<const bf16x8*>(wl + nt * 512);

    // PHASE(kc): prefetch kt=kc+1 into NXT set, compute kt=kc from CUR set.
#define PHASE(BCUR, C0, C1, BNXT, N0, N1R, KC)                                \
    {                                                                         \
        int ktn = (KC) + 1;                                                   \
        int nb = ktn * 32 + hi4 * 8;                                          \
        if (nb > K1 - 8) nb = K1 - 8;  /* pad rows: B is zero there */        \
        N0 = *reinterpret_cast<const float4*>(xr + nb);                       \
        N1R = *reinterpret_cast<const float4*>(xr + nb + 4);                  \
        const ushort* wq = wl + (size_t)ktn * NTT * 512;                      \
        _Pragma("unroll")                                                     \
        for (int nt = 0; nt < NTT; ++nt)                                      \
            BNXT[nt] = *reinterpret_cast<const bf16x8*>(wq + nt * 512);       \
        bf16x8 ah = pack_bf16x8(C0, C1);                                      \
        _Pragma("unroll")                                                     \
        for (int nt = 0; nt < NTT; ++nt)                                      \
            acc[nt] = __builtin_amdgcn_mfma_f32_16x16x32_bf16(ah, BCUR[nt],   \
                                                              acc[nt], 0,0,0);\
    }

    for (int ktp = 0; ktp < (KT - 1) / 2; ++ktp) {          // kt = 0..23
        PHASE(b_e, ce0, ce1, b_o, co0, co1, 2 * ktp);
        PHASE(b_o, co0, co1, b_e, ce0, ce1, 2 * ktp + 1);
    }
    {   // tail kt = 24 (loaded during last odd phase)
        bf16x8 ah = pack_bf16x8(ce0, ce1);
        #pragma unroll
        for (int nt = 0; nt < NTT; ++nt)
            acc[nt] = __builtin_amdgcn_mfma_f32_16x16x32_bf16(ah, b_e[nt],
                                                              acc[nt], 0,0,0);
    }
#undef PHASE

    __syncthreads();   // order staging writes vs epilogue reads (1 wave: free)

    // ---- h1 = relu(acc + b1) in registers.
    // C layout (HW-verified): col = nt*16+lo16, row = hi4*4 + r
    float h1v[NTT][4];
    #pragma unroll
    for (int nt = 0; nt < NTT; ++nt) {
        int col = nt * 16 + lo16;
        bool valid = col < N1;
        float bb = valid ? b1s[valid ? col : 0] : 0.f;
        #pragma unroll
        for (int r = 0; r < 4; ++r)
            h1v[nt][r] = valid ? fmaxf(acc[nt][r] + bb, 0.f) : 0.f;
    }

    // ---- layers 2+3 fused: per j, partial over this lane's 7 cols,
    // xor-reduce across the 16-lane group, accumulate out on the fly.
    const int jj = lo16;                 // this lane's output column (if <10)
    float o[4] = {0.f, 0.f, 0.f, 0.f};
    #pragma unroll
    for (int j = 0; j < 10; ++j) {
        float pj[4] = {0.f, 0.f, 0.f, 0.f};
        #pragma unroll
        for (int nt = 0; nt < NTT; ++nt) {
            float wv = w2t[j][nt * 16 + lo16];   // padded: 0 beyond col 99
            #pragma unroll
            for (int r = 0; r < 4; ++r) pj[r] += h1v[nt][r] * wv;
        }
        #pragma unroll
        for (int mask = 8; mask >= 1; mask >>= 1)
            #pragma unroll
            for (int r = 0; r < 4; ++r)
                pj[r] += __shfl_xor(pj[r], mask, 16);
        float w3v = (jj < 10) ? w3s[j * 10 + jj] : 0.f;
        #pragma unroll
        for (int r = 0; r < 4; ++r) {
            float h2 = fmaxf(pj[r] + b2s[j], 0.f);
            o[r] += h2 * w3v;
        }
    }

    if (jj < 10) {
        #pragma unroll
        for (int r = 0; r < 4; ++r)
            out[(row0 + hi4 * 4 + r) * 10 + jj] = o[r] + b3s[jj];
    }
}

extern "C" void kernel_launch(void* const* d_in, const int* in_sizes, int n_in,
                              void* d_out, int out_size, void* d_ws, size_t ws_size,
                              hipStream_t stream) {
    const float* x     = (const float*)d_in[0];
    const float* convw = (const float*)d_in[1];
    const float* w1    = (const float*)d_in[2];
    const float* b1    = (const float*)d_in[3];
    const float* w2    = (const float*)d_in[4];
    const float* b2    = (const float*)d_in[5];
    const float* w3    = (const float*)d_in[6];
    const float* b3    = (const float*)d_in[7];
    float* out  = (float*)d_out;
    ushort* wp  = (ushort*)d_ws;   // 179,200 B packed W_eff (bf16 RNE)

    build_wp<<<(KT * NTT * 512 + 255) / 256, 256, 0, stream>>>(w1, convw, wp);
    fused_mfma<<<65536 / 16, 64, 0, stream>>>(x, wp, b1, w2, b2, w3, b3, out);
}

// Round 5
// 51.939 us; speedup vs baseline: 7.7358x; 1.2304x over previous
//
#include <hip/hip_runtime.h>
#include <hip/hip_bf16.h>

#define K1 784
#define N1 100
#define KT 25    // k-tiles of 32 (K padded to 800; pad rows zero in packed W)
#define NTT 7    // live n-tiles of 16 (N=100 padded to 112)
#define NTP 8    // stored n-tiles per kt (padded to 8 for 2x global_load_lds)

typedef __attribute__((ext_vector_type(8))) short bf16x8;
typedef __attribute__((ext_vector_type(4))) float f32x4;

__device__ __forceinline__ ushort f2bf(float f) {
    union { float f; unsigned u; } v; v.f = f;
    unsigned u = v.u;
    return (ushort)((u + 0x7FFFu + ((u >> 16) & 1u)) >> 16);   // RNE
}

// 8x f32 -> 8x bf16 (RNE) via 4 packed converts
__device__ __forceinline__ bf16x8 pack_bf16x8(float4 a, float4 b) {
    union { unsigned u[4]; bf16x8 v; } r;
    asm("v_cvt_pk_bf16_f32 %0, %1, %2" : "=v"(r.u[0]) : "v"(a.x), "v"(a.y));
    asm("v_cvt_pk_bf16_f32 %0, %1, %2" : "=v"(r.u[1]) : "v"(a.z), "v"(a.w));
    asm("v_cvt_pk_bf16_f32 %0, %1, %2" : "=v"(r.u[2]) : "v"(b.x), "v"(b.y));
    asm("v_cvt_pk_bf16_f32 %0, %1, %2" : "=v"(r.u[3]) : "v"(b.z), "v"(b.w));
    return r.v;
}

// async 16B global -> LDS (direct, no VGPR round-trip)
__device__ __forceinline__ void gload_lds16(const void* g, void* l) {
    __builtin_amdgcn_global_load_lds(
        (const __attribute__((address_space(1))) void*)g,
        (__attribute__((address_space(3))) void*)l, 16, 0, 0);
}

// ---------------------------------------------------------------------------
// Kernel 1: fold conv into w1 -> W_eff[k][n] (bf16 RNE), stored in MFMA
// B-fragment order: wp[(kt*8+nt)*512 + lane*8 + j] with
//   k = kt*32 + (lane>>4)*8 + j, n = nt*16 + (lane&15).
// nt=7 / k>=784 / n>=100 are zero pad. Total 25*8*512*2B = 204,800 B.
// ---------------------------------------------------------------------------
__global__ void build_wp(const float* __restrict__ w1,
                         const float* __restrict__ conv_w,
                         ushort* __restrict__ wp) {
    int idx = blockIdx.x * blockDim.x + threadIdx.x;
    if (idx >= KT * NTP * 512) return;
    int j = idx & 7, lane = (idx >> 3) & 63, rest = idx >> 9;
    int nt = rest & 7, kt = rest >> 3;
    int k = kt * 32 + (lane >> 4) * 8 + j;
    int n = nt * 16 + (lane & 15);
    float w = 0.f;
    if (k < K1 && n < N1) {
        int py = k / 28, px = k % 28;
        #pragma unroll
        for (int dy = 0; dy < 3; ++dy) {
            int oy = py - dy; if (oy < 0 || oy > 25) continue;
            #pragma unroll
            for (int dx = 0; dx < 3; ++dx) {
                int ox = px - dx; if (ox < 0 || ox > 25) continue;
                w += conv_w[dy * 3 + dx] * w1[(oy * 26 + ox) * N1 + n];
            }
        }
    }
    wp[(size_t)(kt * NTP + nt) * 512 + lane * 8 + j] = f2bf(w);
}

// ---------------------------------------------------------------------------
// Kernel 2: 256-thread blocks (4 waves), 64 rows/block, 1024 blocks
// (= 4 blocks/CU resident, 16 waves/CU). Per kt: B-tile (8 KB) staged into
// double-buffered LDS ONCE per block via global_load_lds; all 4 waves read
// fragments with ds_read_b128. x register-double-buffered per wave.
// One barrier per kt. Epilogue: per-wave shuffle-reduce layers 2/3.
// ---------------------------------------------------------------------------
__global__ __launch_bounds__(256, 4) void fused_mfma(
    const float* __restrict__ x, const ushort* __restrict__ wp,
    const float* __restrict__ b1, const float* __restrict__ w2,
    const float* __restrict__ b2, const float* __restrict__ w3,
    const float* __restrict__ b3, float* __restrict__ out)
{
    __shared__ __attribute__((aligned(16))) ushort bsm[2][NTP * 512]; // 2x8KB
    __shared__ float w2t[10][112];   // transposed w2, padded cols 100..111 = 0
    __shared__ float w3s[100];
    __shared__ float b1s[100];
    __shared__ float b2s[10], b3s[10];

    const int tid  = threadIdx.x;
    const int lane = tid & 63;
    const int lo16 = lane & 15, hi4 = lane >> 4;
    const size_t row0 = (size_t)blockIdx.x * 64 + (tid >> 6) * 16;

    // zero w2t pad, then fill (barrier between to order the two writers)
    for (int e = tid; e < 10 * 112; e += 256) w2t[e / 112][e % 112] = 0.f;
    __syncthreads();
    for (int e = tid; e < 1000; e += 256) w2t[e % 10][e / 10] = w2[e];
    for (int e = tid; e < 100; e += 256) { w3s[e] = w3[e]; b1s[e] = b1[e]; }
    if (tid < 10) { b2s[tid] = b2[tid]; b3s[tid] = b3[tid]; }

    const float* xr = x + (row0 + lo16) * K1;

    f32x4 acc[NTT];
    #pragma unroll
    for (int n = 0; n < NTT; ++n) { f32x4 z = {0.f,0.f,0.f,0.f}; acc[n] = z; }

    // prologue: stage kt=0 B-tile, load kt=0 x
    {
        const ushort* src = wp + tid * 8;
        gload_lds16(src,        &bsm[0][tid * 8]);
        gload_lds16(src + 2048, &bsm[0][tid * 8 + 2048]);
    }
    float4 cur0 = *reinterpret_cast<const float4*>(xr + hi4 * 8);
    float4 cur1 = *reinterpret_cast<const float4*>(xr + hi4 * 8 + 4);
    float4 nxt0 = cur0, nxt1 = cur1;
    __syncthreads();   // bsm[0] staged (barrier drains vmcnt), w2t ready

    for (int kt = 0; kt < KT; ++kt) {
        const int cur = kt & 1;
        if (kt < KT - 1) {
            // stage next B-tile into the other buffer + prefetch next x
            const ushort* src = wp + (size_t)(kt + 1) * (NTP * 512) + tid * 8;
            gload_lds16(src,        &bsm[cur ^ 1][tid * 8]);
            gload_lds16(src + 2048, &bsm[cur ^ 1][tid * 8 + 2048]);
            int nb = (kt + 1) * 32 + hi4 * 8;
            if (nb > K1 - 8) nb = K1 - 8;   // pad region: B rows zero there
            nxt0 = *reinterpret_cast<const float4*>(xr + nb);
            nxt1 = *reinterpret_cast<const float4*>(xr + nb + 4);
        }
        bf16x8 ah = pack_bf16x8(cur0, cur1);
        const ushort* bb = &bsm[cur][lane * 8];
        #pragma unroll
        for (int nt = 0; nt < NTT; ++nt) {
            bf16x8 bh = *reinterpret_cast<const bf16x8*>(bb + nt * 512);
            acc[nt] = __builtin_amdgcn_mfma_f32_16x16x32_bf16(ah, bh,
                                                              acc[nt], 0,0,0);
        }
        __syncthreads();   // next buffer staged + this buffer's reads done
        cur0 = nxt0; cur1 = nxt1;
    }

    // ---- h1 = relu(acc + b1) in registers.
    // C layout (HW-verified): col = nt*16+lo16, row = hi4*4 + r
    float h1v[NTT][4];
    #pragma unroll
    for (int nt = 0; nt < NTT; ++nt) {
        int col = nt * 16 + lo16;
        bool valid = col < N1;
        float bb = valid ? b1s[valid ? col : 0] : 0.f;
        #pragma unroll
        for (int r = 0; r < 4; ++r)
            h1v[nt][r] = valid ? fmaxf(acc[nt][r] + bb, 0.f) : 0.f;
    }

    // ---- layers 2+3 fused: per j, partial over this lane's 7 cols,
    // xor-reduce across the 16-lane group, accumulate out on the fly.
    const int jj = lo16;                 // this lane's output column (if <10)
    float o[4] = {0.f, 0.f, 0.f, 0.f};
    #pragma unroll
    for (int j = 0; j < 10; ++j) {
        float pj[4] = {0.f, 0.f, 0.f, 0.f};
        #pragma unroll
        for (int nt = 0; nt < NTT; ++nt) {
            float wv = w2t[j][nt * 16 + lo16];   // padded: 0 beyond col 99
            #pragma unroll
            for (int r = 0; r < 4; ++r) pj[r] += h1v[nt][r] * wv;
        }
        #pragma unroll
        for (int mask = 8; mask >= 1; mask >>= 1)
            #pragma unroll
            for (int r = 0; r < 4; ++r)
                pj[r] += __shfl_xor(pj[r], mask, 16);
        float w3v = (jj < 10) ? w3s[j * 10 + jj] : 0.f;
        #pragma unroll
        for (int r = 0; r < 4; ++r) {
            float h2 = fmaxf(pj[r] + b2s[j], 0.f);
            o[r] += h2 * w3v;
        }
    }

    if (jj < 10) {
        #pragma unroll
        for (int r = 0; r < 4; ++r)
            out[(row0 + hi4 * 4 + r) * 10 + jj] = o[r] + b3s[jj];
    }
}

extern "C" void kernel_launch(void* const* d_in, const int* in_sizes, int n_in,
                              void* d_out, int out_size, void* d_ws, size_t ws_size,
                              hipStream_t stream) {
    const float* x     = (const float*)d_in[0];
    const float* convw = (const float*)d_in[1];
    const float* w1    = (const float*)d_in[2];
    const float* b1    = (const float*)d_in[3];
    const float* w2    = (const float*)d_in[4];
    const float* b2    = (const float*)d_in[5];
    const float* w3    = (const float*)d_in[6];
    const float* b3    = (const float*)d_in[7];
    float* out  = (float*)d_out;
    ushort* wp  = (ushort*)d_ws;   // 204,800 B packed W_eff (bf16 RNE, 8 nt/kt)

    build_wp<<<(KT * NTP * 512 + 255) / 256, 256, 0, stream>>>(w1, convw, wp);
    fused_mfma<<<65536 / 64, 256, 0, stream>>>(x, wp, b1, w2, b2, w3, b3, out);
}